// Round 5
// baseline (82.328 us; speedup 1.0000x reference)
//
#include <hip/hip_runtime.h>
#include <math.h>

#define Bdim 16
#define Tdim 1024
#define Vdim 2048
#define FEAT (2 * Vdim + 4)   // 4100
#define CONF_THR 0.55f

typedef float f32x4 __attribute__((ext_vector_type(4)));

// One block per output row (b, r). The block recomputes its batch's run
// structure from the 4KB align row (L2-hot), selects the r-th nonblank run
// via bitmask popcount/ffs (uniform across the block), then streams the run's
// frames of shallow/final with gated accumulation. Streaming loads and all
// output stores are nontemporal (read-once / write-once data): keep L2 clean.
__global__ __launch_bounds__(256) void fused_kernel(
    const float* __restrict__ shallow, const float* __restrict__ final_,
    const float* __restrict__ boundary, const int* __restrict__ align,
    const int* __restrict__ lengths,
    float* __restrict__ padded, float* __restrict__ out_len, float* __restrict__ out_conf)
{
    __shared__ int s_lab[Tdim];          // 4 KiB
    __shared__ unsigned int s_chg[32];   // change-flag bitmask over t
    __shared__ unsigned int s_nb[32];    // nonblank-run-start bitmask over t

    const int row = blockIdx.x;
    const int b = row >> 10;
    const int r = row & (Tdim - 1);
    const int tid = threadIdx.x;
    const int length = lengths[b];

    if (tid < 32) { s_chg[tid] = 0u; s_nb[tid] = 0u; }

    // 4 labels per thread, masked to blank beyond length
    const int4 l4 = ((const int4*)(align + b * Tdim))[tid];
    const int t0 = tid * 4;
    const int la0 = (t0 + 0 < length) ? l4.x : 0;
    const int la1 = (t0 + 1 < length) ? l4.y : 0;
    const int la2 = (t0 + 2 < length) ? l4.z : 0;
    const int la3 = (t0 + 3 < length) ? l4.w : 0;
    s_lab[t0 + 0] = la0; s_lab[t0 + 1] = la1;
    s_lab[t0 + 2] = la2; s_lab[t0 + 3] = la3;
    __syncthreads();

    const int prev = (tid == 0) ? -1 : s_lab[t0 - 1];   // labels >= 0 -> t=0 is always a change
    const unsigned c0 = (la0 != prev) ? 1u : 0u;
    const unsigned c1 = (la1 != la0) ? 1u : 0u;
    const unsigned c2 = (la2 != la1) ? 1u : 0u;
    const unsigned c3 = (la3 != la2) ? 1u : 0u;
    const unsigned chg = c0 | (c1 << 1) | (c2 << 2) | (c3 << 3);
    const unsigned nb = (c0 && la0 ? 1u : 0u) | ((c1 && la1 ? 1u : 0u) << 1)
                      | ((c2 && la2 ? 1u : 0u) << 2) | ((c3 && la3 ? 1u : 0u) << 3);
    const unsigned sh = (tid & 7) * 4;   // bit (4*tid+j) lives in word tid/8 at offset (tid&7)*4+j
    if (chg) atomicOr(&s_chg[tid >> 3], chg << sh);
    if (nb)  atomicOr(&s_nb[tid >> 3],  nb << sh);
    __syncthreads();

    // nseg (redundant on all threads)
    int nseg = 0;
    #pragma unroll
    for (int w = 0; w < 32; ++w) nseg += __popc(s_nb[w]);

    float* out = padded + (size_t)row * FEAT;
    f32x4* o4 = (f32x4*)out;

    if (r >= nseg) {
        const f32x4 z = (f32x4)(0.f);
        #pragma unroll
        for (int i = 0; i < 4; ++i)
            __builtin_nontemporal_store(z, o4 + tid + 256 * i);
        if (tid == 0) {
            __builtin_nontemporal_store(z, o4 + 1024);
            out_conf[row] = (r == 0 && nseg == 0) ? 1.0f : 0.0f;
            if (r == 0) out_len[b] = 1.0f;   // nseg==0 fallback (r==0 lands here only then)
        }
        return;
    }

    // start = position of the (r+1)-th set bit in s_nb (uniform, redundant)
    int start;
    {
        int need = r;
        int w = 0;
        for (; w < 32; ++w) {
            const int c = __popc(s_nb[w]);
            if (need < c) break;
            need -= c;
        }
        unsigned word = s_nb[w];
        for (int k = 0; k < need; ++k) word &= word - 1;
        start = w * 32 + __ffs(word) - 1;
    }
    // end = first change strictly after start (else Tdim)
    int end = Tdim;
    {
        const int p = start + 1;
        int w = p >> 5;
        if (w < 32) {
            unsigned word = s_chg[w] & (0xFFFFFFFFu << (p & 31));
            while (word == 0u && ++w < 32) word = s_chg[w];
            if (word) end = w * 32 + __ffs(word) - 1;
        }
    }

    const int lab = s_lab[start];
    const int cnt = end - start;
    const float left_b  = (r == 0) ? 1.0f : boundary[b * Tdim + start - 1];
    const float right_b = boundary[b * Tdim + end - 1];
    const float scale = 1.0f + 0.25f * (1.0f - left_b) + 0.25f * (1.0f - right_b);

    f32x4 aS0 = (f32x4)(0.f), aS1 = (f32x4)(0.f), aF0 = (f32x4)(0.f), aF1 = (f32x4)(0.f);
    float gsum = 0.f, fcsum = 0.f, ssum = 0.f;
    const float* sRow = shallow + ((size_t)(b * Tdim) + start) * Vdim;
    const float* fRow = final_  + ((size_t)(b * Tdim) + start) * Vdim;

    for (int f = 0; f < cnt; ++f) {
        const f32x4* s4 = (const f32x4*)sRow;
        const f32x4* f4 = (const f32x4*)fRow;
        const float sv = sRow[lab];         // same-address broadcast (normal caching)
        const float fv = fRow[lab];
        const f32x4 s0 = __builtin_nontemporal_load(s4 + tid);
        const f32x4 s1 = __builtin_nontemporal_load(s4 + tid + 256);
        const f32x4 f0 = __builtin_nontemporal_load(f4 + tid);
        const f32x4 f1 = __builtin_nontemporal_load(f4 + tid + 256);
        const float fc = 0.5f * (sv + fv);
        const float g = 1.0f / (1.0f + __expf(-(fc - CONF_THR) * 12.0f)) + 0.05f;
        gsum += g; fcsum += fc; ssum += sv;
        aS0 += s0 * g; aS1 += s1 * g; aF0 += f0 * g; aF1 += f1 * g;
        sRow += Vdim; fRow += Vdim;
    }

    const float m = scale / fmaxf(gsum, 1e-6f);
    __builtin_nontemporal_store(aS0 * m, o4 + tid);
    __builtin_nontemporal_store(aS1 * m, o4 + tid + 256);
    __builtin_nontemporal_store(aF0 * m, o4 + tid + 512);
    __builtin_nontemporal_store(aF1 * m, o4 + tid + 768);
    if (tid == 0) {
        const float inv_cnt = 1.0f / (float)cnt;
        const float seg_conf = fcsum * inv_cnt;
        f32x4 e;
        e.x = seg_conf * scale;
        e.y = (ssum * inv_cnt) * scale;
        e.z = left_b * scale;
        e.w = right_b * scale;
        __builtin_nontemporal_store(e, o4 + 1024);
        out_conf[row] = fminf(fmaxf(seg_conf, 0.05f), 1.0f);
        if (r == 0) out_len[b] = (float)nseg;
    }
}

extern "C" void kernel_launch(void* const* d_in, const int* in_sizes, int n_in,
                              void* d_out, int out_size, void* d_ws, size_t ws_size,
                              hipStream_t stream) {
    const float* shallow  = (const float*)d_in[0];
    const float* final_   = (const float*)d_in[1];
    const float* boundary = (const float*)d_in[2];
    const int*   align    = (const int*)d_in[3];
    const int*   lengths  = (const int*)d_in[4];

    float* out = (float*)d_out;
    float* padded   = out;                                       // [B, T, FEAT]
    float* out_len  = out + (size_t)Bdim * Tdim * FEAT;          // [B]
    float* out_conf = out_len + Bdim;                            // [B, T]

    fused_kernel<<<Bdim * Tdim, 256, 0, stream>>>(shallow, final_, boundary, align,
                                                  lengths, padded, out_len, out_conf);
}

// Round 8
// 67.391 us; speedup vs baseline: 1.2216x; 1.2216x over previous
//
#include <hip/hip_runtime.h>
#include <math.h>

#define Bdim 16
#define Tdim 1024
#define Vdim 2048
#define FEAT (2 * Vdim + 4)   // 4100
#define CONF_THR 0.55f

typedef float f32x4 __attribute__((ext_vector_type(4)));

// One block per output row (b, r). The block recomputes its batch's run
// structure from the 4KB align row (L2-hot), selects the r-th nonblank run
// via bitmask popcount/ffs (uniform across the block), then streams the run's
// frames of shallow/final with gated accumulation.
// Loads: NORMAL caching (inputs are L3-resident across graph replays; NT loads
// measured -23% in round 5). Stores: nontemporal (write-once, never re-read).
// Rows with r >= length are provably zero (nseg <= length): skip scan entirely.
__global__ __launch_bounds__(256) void fused_kernel(
    const float* __restrict__ shallow, const float* __restrict__ final_,
    const float* __restrict__ boundary, const int* __restrict__ align,
    const int* __restrict__ lengths,
    float* __restrict__ padded, float* __restrict__ out_len, float* __restrict__ out_conf)
{
    __shared__ int s_lab[Tdim];          // 4 KiB
    __shared__ unsigned int s_chg[32];   // change-flag bitmask over t
    __shared__ unsigned int s_nb[32];    // nonblank-run-start bitmask over t

    const int row = blockIdx.x;
    const int b = row >> 10;
    const int r = row & (Tdim - 1);
    const int tid = threadIdx.x;
    const int length = lengths[b];

    float* out = padded + (size_t)row * FEAT;
    f32x4* o4 = (f32x4*)out;

    // fast path: r >= length implies r >= nseg (nseg <= length, and length >= 1
    // so this never hits the r==0 empty-utterance fallback). Pure zero-writer.
    if (r >= length) {
        const f32x4 z = (f32x4)(0.f);
        #pragma unroll
        for (int i = 0; i < 4; ++i)
            __builtin_nontemporal_store(z, o4 + tid + 256 * i);
        if (tid == 0) {
            __builtin_nontemporal_store(z, o4 + 1024);
            out_conf[row] = 0.0f;
        }
        return;
    }

    if (tid < 32) { s_chg[tid] = 0u; s_nb[tid] = 0u; }

    // 4 labels per thread, masked to blank beyond length
    const int4 l4 = ((const int4*)(align + b * Tdim))[tid];
    const int t0 = tid * 4;
    const int la0 = (t0 + 0 < length) ? l4.x : 0;
    const int la1 = (t0 + 1 < length) ? l4.y : 0;
    const int la2 = (t0 + 2 < length) ? l4.z : 0;
    const int la3 = (t0 + 3 < length) ? l4.w : 0;
    s_lab[t0 + 0] = la0; s_lab[t0 + 1] = la1;
    s_lab[t0 + 2] = la2; s_lab[t0 + 3] = la3;
    __syncthreads();

    const int prev = (tid == 0) ? -1 : s_lab[t0 - 1];   // labels >= 0 -> t=0 is always a change
    const unsigned c0 = (la0 != prev) ? 1u : 0u;
    const unsigned c1 = (la1 != la0) ? 1u : 0u;
    const unsigned c2 = (la2 != la1) ? 1u : 0u;
    const unsigned c3 = (la3 != la2) ? 1u : 0u;
    const unsigned chg = c0 | (c1 << 1) | (c2 << 2) | (c3 << 3);
    const unsigned nb = (c0 && la0 ? 1u : 0u) | ((c1 && la1 ? 1u : 0u) << 1)
                      | ((c2 && la2 ? 1u : 0u) << 2) | ((c3 && la3 ? 1u : 0u) << 3);
    const unsigned sh = (tid & 7) * 4;   // bit (4*tid+j) lives in word tid/8 at offset (tid&7)*4+j
    if (chg) atomicOr(&s_chg[tid >> 3], chg << sh);
    if (nb)  atomicOr(&s_nb[tid >> 3],  nb << sh);
    __syncthreads();

    // nseg (redundant on all threads)
    int nseg = 0;
    #pragma unroll
    for (int w = 0; w < 32; ++w) nseg += __popc(s_nb[w]);

    if (r >= nseg) {
        const f32x4 z = (f32x4)(0.f);
        #pragma unroll
        for (int i = 0; i < 4; ++i)
            __builtin_nontemporal_store(z, o4 + tid + 256 * i);
        if (tid == 0) {
            __builtin_nontemporal_store(z, o4 + 1024);
            out_conf[row] = (r == 0 && nseg == 0) ? 1.0f : 0.0f;
            if (r == 0) out_len[b] = 1.0f;   // nseg==0 fallback (r==0 lands here only then)
        }
        return;
    }

    // start = position of the (r+1)-th set bit in s_nb (uniform, redundant)
    int start;
    {
        int need = r;
        int w = 0;
        for (; w < 32; ++w) {
            const int c = __popc(s_nb[w]);
            if (need < c) break;
            need -= c;
        }
        unsigned word = s_nb[w];
        for (int k = 0; k < need; ++k) word &= word - 1;
        start = w * 32 + __ffs(word) - 1;
    }
    // end = first change strictly after start (else Tdim)
    int end = Tdim;
    {
        const int p = start + 1;
        int w = p >> 5;
        if (w < 32) {
            unsigned word = s_chg[w] & (0xFFFFFFFFu << (p & 31));
            while (word == 0u && ++w < 32) word = s_chg[w];
            if (word) end = w * 32 + __ffs(word) - 1;
        }
    }

    const int lab = s_lab[start];
    const int cnt = end - start;
    const float left_b  = (r == 0) ? 1.0f : boundary[b * Tdim + start - 1];
    const float right_b = boundary[b * Tdim + end - 1];
    const float scale = 1.0f + 0.25f * (1.0f - left_b) + 0.25f * (1.0f - right_b);

    f32x4 aS0 = (f32x4)(0.f), aS1 = (f32x4)(0.f), aF0 = (f32x4)(0.f), aF1 = (f32x4)(0.f);
    float gsum = 0.f, fcsum = 0.f, ssum = 0.f;
    const float* sRow = shallow + ((size_t)(b * Tdim) + start) * Vdim;
    const float* fRow = final_  + ((size_t)(b * Tdim) + start) * Vdim;

    for (int f = 0; f < cnt; ++f) {
        const f32x4* s4 = (const f32x4*)sRow;
        const f32x4* f4 = (const f32x4*)fRow;
        const float sv = sRow[lab];         // same-address broadcast, line is streamed anyway
        const float fv = fRow[lab];
        const f32x4 s0 = s4[tid];
        const f32x4 s1 = s4[tid + 256];
        const f32x4 f0 = f4[tid];
        const f32x4 f1 = f4[tid + 256];
        const float fc = 0.5f * (sv + fv);
        const float g = 1.0f / (1.0f + __expf(-(fc - CONF_THR) * 12.0f)) + 0.05f;
        gsum += g; fcsum += fc; ssum += sv;
        aS0 += s0 * g; aS1 += s1 * g; aF0 += f0 * g; aF1 += f1 * g;
        sRow += Vdim; fRow += Vdim;
    }

    const float m = scale / fmaxf(gsum, 1e-6f);
    __builtin_nontemporal_store(aS0 * m, o4 + tid);
    __builtin_nontemporal_store(aS1 * m, o4 + tid + 256);
    __builtin_nontemporal_store(aF0 * m, o4 + tid + 512);
    __builtin_nontemporal_store(aF1 * m, o4 + tid + 768);
    if (tid == 0) {
        const float inv_cnt = 1.0f / (float)cnt;
        const float seg_conf = fcsum * inv_cnt;
        f32x4 e;
        e.x = seg_conf * scale;
        e.y = (ssum * inv_cnt) * scale;
        e.z = left_b * scale;
        e.w = right_b * scale;
        __builtin_nontemporal_store(e, o4 + 1024);
        out_conf[row] = fminf(fmaxf(seg_conf, 0.05f), 1.0f);
        if (r == 0) out_len[b] = (float)nseg;
    }
}

extern "C" void kernel_launch(void* const* d_in, const int* in_sizes, int n_in,
                              void* d_out, int out_size, void* d_ws, size_t ws_size,
                              hipStream_t stream) {
    const float* shallow  = (const float*)d_in[0];
    const float* final_   = (const float*)d_in[1];
    const float* boundary = (const float*)d_in[2];
    const int*   align    = (const int*)d_in[3];
    const int*   lengths  = (const int*)d_in[4];

    float* out = (float*)d_out;
    float* padded   = out;                                       // [B, T, FEAT]
    float* out_len  = out + (size_t)Bdim * Tdim * FEAT;          // [B]
    float* out_conf = out_len + Bdim;                            // [B, T]

    fused_kernel<<<Bdim * Tdim, 256, 0, stream>>>(shallow, final_, boundary, align,
                                                  lengths, padded, out_len, out_conf);
}